// Round 2
// baseline (746.668 us; speedup 1.0000x reference)
//
#include <hip/hip_runtime.h>
#include <hip/hip_bf16.h>

// Shapes: B=8 N=1024 C=768 H=12 D=64; qkv out = 2304; tokens = 8192.
// d_out = [out f32 6291456][attn_probs f32 100663296]
// ws layout (bytes): xb 0 | wqkvb 12582912 | wprojb 16121856 | q 17301504 |
//                    k 29884416 | vt 42467328 | ao 55050240 | end 67633152

typedef unsigned short u16;
typedef __attribute__((ext_vector_type(8))) short bf16x8;
typedef __attribute__((ext_vector_type(4))) float f32x4;

#define DEVI static __device__ __forceinline__

DEVI u16 f2bf(float f) {
  union { float f; unsigned int u; } v; v.f = f;
  return (u16)((v.u + 0x7fffu + ((v.u >> 16) & 1u)) >> 16);
}

DEVI void gload16(const void* g, void* l) {
  __builtin_amdgcn_global_load_lds(
      (const __attribute__((address_space(1))) unsigned int*)g,
      (__attribute__((address_space(3))) unsigned int*)l, 16, 0, 0);
}

// ---------------- f32 -> bf16 convert (4 elems/thread) ----------------
__global__ void cvt_f32_bf16(const float* __restrict__ src, u16* __restrict__ dst, int n4) {
  int i = blockIdx.x * 256 + threadIdx.x;
  if (i >= n4) return;
  float4 f = ((const float4*)src)[i];
  unsigned int lo = f2bf(f.x) | ((unsigned int)f2bf(f.y) << 16);
  unsigned int hi = f2bf(f.z) | ((unsigned int)f2bf(f.w) << 16);
  ((uint2*)dst)[i] = make_uint2(lo, hi);
}

// ---------------- 128x128 bf16 GEMM, C = A * Bw^T (both K-contig) ------
// MODE 0: qkv epilogue (scatter q*0.125 / k+se / v^T), MODE 1: proj (+bias, f32 out)
template<int MODE>
__global__ __launch_bounds__(256)
void gemm128(const u16* __restrict__ A, const u16* __restrict__ Bw, int K,
             const float* __restrict__ se,
             u16* __restrict__ qo, u16* __restrict__ ko, u16* __restrict__ vto,
             const float* __restrict__ bias, float* __restrict__ out)
{
  __shared__ u16 lA[128 * 32];
  __shared__ u16 lB[128 * 32];
  const int mt = blockIdx.x, nt = blockIdx.y;
  const int t = threadIdx.x;
  const int w = t >> 6, l = t & 63, lhi = l >> 4, llo = l & 15;
  const int wr = w >> 1, wc = w & 1;

  f32x4 acc[4][4];
#pragma unroll
  for (int m = 0; m < 4; ++m)
#pragma unroll
    for (int n = 0; n < 4; ++n) acc[m][n] = f32x4{0.f, 0.f, 0.f, 0.f};

  const size_t arow0 = (size_t)mt * 128, brow0 = (size_t)nt * 128;

  for (int k0 = 0; k0 < K; k0 += 32) {
#pragma unroll
    for (int r = 0; r < 2; ++r) {
      int idx = r * 256 + t;
      int row = idx >> 2, col = (idx & 3) * 8;
      gload16(A + (arow0 + row) * K + k0 + col, &lA[idx * 8]);
      gload16(Bw + (brow0 + row) * K + k0 + col, &lB[idx * 8]);
    }
    __syncthreads();  // drains vmcnt (global_load_lds) + barrier
    bf16x8 af[4], bfr[4];
#pragma unroll
    for (int m = 0; m < 4; ++m)
      af[m] = *(const bf16x8*)&lA[(wr * 64 + m * 16 + llo) * 32 + lhi * 8];
#pragma unroll
    for (int n = 0; n < 4; ++n)
      bfr[n] = *(const bf16x8*)&lB[(wc * 64 + n * 16 + llo) * 32 + lhi * 8];
#pragma unroll
    for (int m = 0; m < 4; ++m)
#pragma unroll
      for (int n = 0; n < 4; ++n)
        acc[m][n] = __builtin_amdgcn_mfma_f32_16x16x32_bf16(af[m], bfr[n], acc[m][n], 0, 0, 0);
    __syncthreads();  // protect LDS before next stage
  }

  if (MODE == 0) {
    const int part = nt / 6;  // 0=q 1=k 2=v (768 = 6 tiles of 128)
#pragma unroll
    for (int n = 0; n < 4; ++n) {
      const int gcol = (int)brow0 + wc * 64 + n * 16 + llo;
      const int c = gcol - part * 768;
      const int h = c >> 6, d = c & 63;
      const float sev = (part == 1) ? se[c] : 0.f;
#pragma unroll
      for (int m = 0; m < 4; ++m) {
#pragma unroll
        for (int j = 0; j < 4; ++j) {
          const int tok = (int)arow0 + wr * 64 + m * 16 + lhi * 4 + j;
          const int b = tok >> 10, ntok = tok & 1023;
          const size_t bhh = (size_t)(b * 12 + h);
          const float v = acc[m][n][j];
          if (part == 0)      qo[(bhh * 1024 + ntok) * 64 + d] = f2bf(v * 0.125f);
          else if (part == 1) ko[(bhh * 1024 + ntok) * 64 + d] = f2bf(v + sev);
          else                vto[(bhh * 64 + d) * 1024 + ntok] = f2bf(v);
        }
      }
    }
  } else {
#pragma unroll
    for (int m = 0; m < 4; ++m)
#pragma unroll
      for (int j = 0; j < 4; ++j) {
        const int tok = (int)arow0 + wr * 64 + m * 16 + lhi * 4 + j;
#pragma unroll
        for (int n = 0; n < 4; ++n) {
          const int gcol = (int)brow0 + wc * 64 + n * 16 + llo;
          out[(size_t)tok * 768 + gcol] = acc[m][n][j] + bias[gcol];
        }
      }
  }
}

// ---------------- fused S = (q*scale) K^T + row softmax -> probs f32 ----
// block = (qt 32 rows, bh). 4 waves; wave w owns cols [w*64, w*64+64) per
// 256-col K-chunk. S kept in registers: acc[4 chunks][2 m][4 n] = 128 VGPR.
// K chunk reg-staged into LDS with XOR swizzle (row-major [256][128B] would
// be a 16-way bank conflict on ds_read_b128 otherwise).
__global__ __launch_bounds__(256)
void attn_sm(const u16* __restrict__ q, const u16* __restrict__ kin,
             float* __restrict__ probs)
{
  __shared__ u16 lq[32 * 64];
  __shared__ u16 lk[256 * 64];
  __shared__ float red[4][32];
  const int qt = blockIdx.x, bh = blockIdx.y;
  const int t = threadIdx.x;
  const int w = t >> 6, l = t & 63, lhi = l >> 4, llo = l & 15;

  gload16(q + ((size_t)bh * 1024 + qt * 32) * 64 + t * 8, &lq[t * 8]);
  __syncthreads();

  bf16x8 aq[2][2];
#pragma unroll
  for (int m = 0; m < 2; ++m)
#pragma unroll
    for (int kc = 0; kc < 2; ++kc)
      aq[m][kc] = *(const bf16x8*)&lq[(m * 16 + llo) * 64 + kc * 32 + lhi * 8];

  f32x4 acc[4][2][4];
#pragma unroll
  for (int c = 0; c < 4; ++c)
#pragma unroll
    for (int m = 0; m < 2; ++m)
#pragma unroll
      for (int n = 0; n < 4; ++n) acc[c][m][n] = f32x4{0.f, 0.f, 0.f, 0.f};

#pragma unroll
  for (int c = 0; c < 4; ++c) {
    __syncthreads();  // protect lk reads of previous chunk
#pragma unroll
    for (int r = 0; r < 8; ++r) {
      int idx = r * 256 + t;
      int row = idx >> 3;
      int cb = (idx & 7) * 16;  // byte col in 128B row
      bf16x8 val = *(const bf16x8*)(kin + ((size_t)bh * 1024 + c * 256 + row) * 64 + (idx & 7) * 8);
      *(bf16x8*)((char*)lk + row * 128 + (cb ^ ((row & 7) << 4))) = val;
    }
    __syncthreads();
#pragma unroll
    for (int n = 0; n < 4; ++n) {
      const int row = w * 64 + n * 16 + llo;
      const char* rp = (const char*)lk + row * 128;
      const int sw = (row & 7) << 4;
      bf16x8 b0 = *(const bf16x8*)(rp + ((lhi * 16) ^ sw));
      bf16x8 b1 = *(const bf16x8*)(rp + ((64 + lhi * 16) ^ sw));
#pragma unroll
      for (int m = 0; m < 2; ++m) {
        acc[c][m][n] = __builtin_amdgcn_mfma_f32_16x16x32_bf16(aq[m][0], b0, acc[c][m][n], 0, 0, 0);
        acc[c][m][n] = __builtin_amdgcn_mfma_f32_16x16x32_bf16(aq[m][1], b1, acc[c][m][n], 0, 0, 0);
      }
    }
  }

  // ---- row max: per-lane over its 16 cols, xor-reduce 16 lanes, LDS cross-wave
  float rmx[2][4];
#pragma unroll
  for (int m = 0; m < 2; ++m)
#pragma unroll
    for (int j = 0; j < 4; ++j) {
      float v = -1e30f;
#pragma unroll
      for (int c = 0; c < 4; ++c)
#pragma unroll
        for (int n = 0; n < 4; ++n) v = fmaxf(v, acc[c][m][n][j]);
      rmx[m][j] = v;
    }
#pragma unroll
  for (int msk = 1; msk < 16; msk <<= 1)
#pragma unroll
    for (int m = 0; m < 2; ++m)
#pragma unroll
      for (int j = 0; j < 4; ++j)
        rmx[m][j] = fmaxf(rmx[m][j], __shfl_xor(rmx[m][j], msk));
  if (llo == 0) {
#pragma unroll
    for (int m = 0; m < 2; ++m)
#pragma unroll
      for (int j = 0; j < 4; ++j) red[w][m * 16 + lhi * 4 + j] = rmx[m][j];
  }
  __syncthreads();
  float fmx[2][4];
#pragma unroll
  for (int m = 0; m < 2; ++m)
#pragma unroll
    for (int j = 0; j < 4; ++j) {
      int r = m * 16 + lhi * 4 + j;
      fmx[m][j] = fmaxf(fmaxf(red[0][r], red[1][r]), fmaxf(red[2][r], red[3][r]));
    }
  __syncthreads();  // before reusing red for sums

  // ---- exp + row sum
  float rsm[2][4];
#pragma unroll
  for (int m = 0; m < 2; ++m)
#pragma unroll
    for (int j = 0; j < 4; ++j) rsm[m][j] = 0.f;
#pragma unroll
  for (int c = 0; c < 4; ++c)
#pragma unroll
    for (int n = 0; n < 4; ++n)
#pragma unroll
      for (int m = 0; m < 2; ++m)
#pragma unroll
        for (int j = 0; j < 4; ++j) {
          float e = __expf(acc[c][m][n][j] - fmx[m][j]);
          acc[c][m][n][j] = e;
          rsm[m][j] += e;
        }
#pragma unroll
  for (int msk = 1; msk < 16; msk <<= 1)
#pragma unroll
    for (int m = 0; m < 2; ++m)
#pragma unroll
      for (int j = 0; j < 4; ++j) rsm[m][j] += __shfl_xor(rsm[m][j], msk);
  if (llo == 0) {
#pragma unroll
    for (int m = 0; m < 2; ++m)
#pragma unroll
      for (int j = 0; j < 4; ++j) red[w][m * 16 + lhi * 4 + j] = rsm[m][j];
  }
  __syncthreads();
  float inv[2][4];
#pragma unroll
  for (int m = 0; m < 2; ++m)
#pragma unroll
    for (int j = 0; j < 4; ++j) {
      int r = m * 16 + lhi * 4 + j;
      inv[m][j] = 1.0f / (red[0][r] + red[1][r] + red[2][r] + red[3][r]);
    }

  // ---- write probs f32
  float* pb = probs + ((size_t)bh * 1024 + qt * 32) * 1024;
#pragma unroll
  for (int c = 0; c < 4; ++c)
#pragma unroll
    for (int n = 0; n < 4; ++n) {
      const int col = c * 256 + w * 64 + n * 16 + llo;
#pragma unroll
      for (int m = 0; m < 2; ++m)
#pragma unroll
        for (int j = 0; j < 4; ++j) {
          const int r = m * 16 + lhi * 4 + j;
          pb[(size_t)r * 1024 + col] = acc[c][m][n][j] * inv[m][j];
        }
    }
}

// ---------------- PV: ao[b,n,h*64+d] = probs(f32->bf16) @ v^T -----------
// No LDS: A-frags from global f32 probs (converted in-reg), B-frags from v^T.
__global__ __launch_bounds__(256)
void pv_gemm(const float* __restrict__ probs, const u16* __restrict__ vt,
             u16* __restrict__ ao)
{
  const int mt = blockIdx.x, bh = blockIdx.y;
  const int t = threadIdx.x;
  const int w = t >> 6, l = t & 63, lhi = l >> 4, llo = l & 15;
  const int b = bh / 12, h = bh % 12;

  f32x4 acc[2][4];
#pragma unroll
  for (int m = 0; m < 2; ++m)
#pragma unroll
    for (int n = 0; n < 4; ++n) acc[m][n] = f32x4{0.f, 0.f, 0.f, 0.f};

  const float* pb = probs + ((size_t)bh * 1024 + mt * 128 + w * 32) * 1024;
  const u16* vb = vt + (size_t)bh * 65536;

  for (int k0 = 0; k0 < 1024; k0 += 32) {
    bf16x8 a[2], v[4];
#pragma unroll
    for (int m = 0; m < 2; ++m) {
      const float* p = pb + (size_t)(m * 16 + llo) * 1024 + k0 + lhi * 8;
      float4 f0 = *(const float4*)p;
      float4 f1 = *(const float4*)(p + 4);
      bf16x8 r;
      r[0] = (short)f2bf(f0.x); r[1] = (short)f2bf(f0.y);
      r[2] = (short)f2bf(f0.z); r[3] = (short)f2bf(f0.w);
      r[4] = (short)f2bf(f1.x); r[5] = (short)f2bf(f1.y);
      r[6] = (short)f2bf(f1.z); r[7] = (short)f2bf(f1.w);
      a[m] = r;
    }
#pragma unroll
    for (int n = 0; n < 4; ++n)
      v[n] = *(const bf16x8*)(vb + (size_t)(n * 16 + llo) * 1024 + k0 + lhi * 8);
#pragma unroll
    for (int m = 0; m < 2; ++m)
#pragma unroll
      for (int n = 0; n < 4; ++n)
        acc[m][n] = __builtin_amdgcn_mfma_f32_16x16x32_bf16(a[m], v[n], acc[m][n], 0, 0, 0);
  }
#pragma unroll
  for (int m = 0; m < 2; ++m)
#pragma unroll
    for (int n = 0; n < 4; ++n)
#pragma unroll
      for (int j = 0; j < 4; ++j) {
        const int ntok = mt * 128 + w * 32 + m * 16 + lhi * 4 + j;
        const int d = n * 16 + llo;
        ao[((size_t)(b * 1024 + ntok)) * 768 + h * 64 + d] = f2bf(acc[m][n][j]);
      }
}

// ------------------------------- launch --------------------------------
extern "C" void kernel_launch(void* const* d_in, const int* in_sizes, int n_in,
                              void* d_out, int out_size, void* d_ws, size_t ws_size,
                              hipStream_t stream) {
  const float* x     = (const float*)d_in[0];
  const float* se    = (const float*)d_in[1];
  const float* wqkv  = (const float*)d_in[2];
  const float* wproj = (const float*)d_in[3];
  const float* bproj = (const float*)d_in[4];
  float* out = (float*)d_out;
  float* probs = out + 6291456;

  if (ws_size < 67633152) return;  // need ~64.5 MB scratch
  char* ws = (char*)d_ws;
  u16* xb     = (u16*)(ws);
  u16* wqkvb  = (u16*)(ws + 12582912);
  u16* wprojb = (u16*)(ws + 16121856);
  u16* qb     = (u16*)(ws + 17301504);
  u16* kb     = (u16*)(ws + 29884416);
  u16* vtb    = (u16*)(ws + 42467328);
  u16* aob    = (u16*)(ws + 55050240);

  cvt_f32_bf16<<<6144, 256, 0, stream>>>(x, xb, 1572864);
  cvt_f32_bf16<<<1728, 256, 0, stream>>>(wqkv, wqkvb, 442368);
  cvt_f32_bf16<<<576, 256, 0, stream>>>(wprojb == nullptr ? wproj : wproj, wprojb, 147456);
  gemm128<0><<<dim3(64, 18), 256, 0, stream>>>(xb, wqkvb, 768, se, qb, kb, vtb, nullptr, nullptr);
  attn_sm<<<dim3(32, 96), 256, 0, stream>>>(qb, kb, probs);
  pv_gemm<<<dim3(8, 96), 256, 0, stream>>>(probs, vtb, aob);
  gemm128<1><<<dim3(64, 6), 256, 0, stream>>>(aob, wprojb, 768, nullptr, nullptr, nullptr, nullptr, bproj, out);
}

// Round 3
// 724.476 us; speedup vs baseline: 1.0306x; 1.0306x over previous
//
#include <hip/hip_runtime.h>
#include <hip/hip_bf16.h>

// Shapes: B=8 N=1024 C=768 H=12 D=64; qkv out = 2304; tokens = 8192.
// d_out = [out f32 6291456][attn_probs f32 100663296]
// ws layout (bytes): xb 0 | wqkvb 12582912 | wprojb 16121856 | q 17301504 |
//                    k 29884416 | vt 42467328 | ao 55050240 | end 67633152

typedef unsigned short u16;
typedef __attribute__((ext_vector_type(8))) short bf16x8;
typedef __attribute__((ext_vector_type(4))) float f32x4;

#define DEVI static __device__ __forceinline__

DEVI u16 f2bf(float f) {
  union { float f; unsigned int u; } v; v.f = f;
  return (u16)((v.u + 0x7fffu + ((v.u >> 16) & 1u)) >> 16);
}

DEVI void gload16(const void* g, void* l) {
  __builtin_amdgcn_global_load_lds(
      (const __attribute__((address_space(1))) unsigned int*)g,
      (__attribute__((address_space(3))) unsigned int*)l, 16, 0, 0);
}

// ---------------- f32 -> bf16 convert (4 elems/thread) ----------------
__global__ void cvt_f32_bf16(const float* __restrict__ src, u16* __restrict__ dst, int n4) {
  int i = blockIdx.x * 256 + threadIdx.x;
  if (i >= n4) return;
  float4 f = ((const float4*)src)[i];
  unsigned int lo = f2bf(f.x) | ((unsigned int)f2bf(f.y) << 16);
  unsigned int hi = f2bf(f.z) | ((unsigned int)f2bf(f.w) << 16);
  ((uint2*)dst)[i] = make_uint2(lo, hi);
}

// ---------------- 128x128 bf16 GEMM, C = A * Bw^T (both K-contig) ------
// MODE 0: qkv epilogue (scatter q*0.125 / k+se / v^T), MODE 1: proj (+bias, f32 out)
template<int MODE>
__global__ __launch_bounds__(256)
void gemm128(const u16* __restrict__ A, const u16* __restrict__ Bw, int K,
             const float* __restrict__ se,
             u16* __restrict__ qo, u16* __restrict__ ko, u16* __restrict__ vto,
             const float* __restrict__ bias, float* __restrict__ out)
{
  __shared__ u16 lA[128 * 32];
  __shared__ u16 lB[128 * 32];
  const int mt = blockIdx.x, nt = blockIdx.y;
  const int t = threadIdx.x;
  const int w = t >> 6, l = t & 63, lhi = l >> 4, llo = l & 15;
  const int wr = w >> 1, wc = w & 1;

  f32x4 acc[4][4];
#pragma unroll
  for (int m = 0; m < 4; ++m)
#pragma unroll
    for (int n = 0; n < 4; ++n) acc[m][n] = f32x4{0.f, 0.f, 0.f, 0.f};

  const size_t arow0 = (size_t)mt * 128, brow0 = (size_t)nt * 128;

  for (int k0 = 0; k0 < K; k0 += 32) {
#pragma unroll
    for (int r = 0; r < 2; ++r) {
      int idx = r * 256 + t;
      int row = idx >> 2, col = (idx & 3) * 8;
      gload16(A + (arow0 + row) * K + k0 + col, &lA[idx * 8]);
      gload16(Bw + (brow0 + row) * K + k0 + col, &lB[idx * 8]);
    }
    __syncthreads();  // drains vmcnt (global_load_lds) + barrier
    bf16x8 af[4], bfr[4];
#pragma unroll
    for (int m = 0; m < 4; ++m)
      af[m] = *(const bf16x8*)&lA[(wr * 64 + m * 16 + llo) * 32 + lhi * 8];
#pragma unroll
    for (int n = 0; n < 4; ++n)
      bfr[n] = *(const bf16x8*)&lB[(wc * 64 + n * 16 + llo) * 32 + lhi * 8];
#pragma unroll
    for (int m = 0; m < 4; ++m)
#pragma unroll
      for (int n = 0; n < 4; ++n)
        acc[m][n] = __builtin_amdgcn_mfma_f32_16x16x32_bf16(af[m], bfr[n], acc[m][n], 0, 0, 0);
    __syncthreads();  // protect LDS before next stage
  }

  if (MODE == 0) {
    const int part = nt / 6;  // 0=q 1=k 2=v (768 = 6 tiles of 128)
#pragma unroll
    for (int n = 0; n < 4; ++n) {
      const int gcol = (int)brow0 + wc * 64 + n * 16 + llo;
      const int c = gcol - part * 768;
      const int h = c >> 6, d = c & 63;
      const float sev = (part == 1) ? se[c] : 0.f;
#pragma unroll
      for (int m = 0; m < 4; ++m) {
#pragma unroll
        for (int j = 0; j < 4; ++j) {
          const int tok = (int)arow0 + wr * 64 + m * 16 + lhi * 4 + j;
          const int b = tok >> 10, ntok = tok & 1023;
          const size_t bhh = (size_t)(b * 12 + h);
          const float v = acc[m][n][j];
          if (part == 0)      qo[(bhh * 1024 + ntok) * 64 + d] = f2bf(v * 0.125f);
          else if (part == 1) ko[(bhh * 1024 + ntok) * 64 + d] = f2bf(v + sev);
          else                vto[(bhh * 64 + d) * 1024 + ntok] = f2bf(v);
        }
      }
    }
  } else {
#pragma unroll
    for (int m = 0; m < 4; ++m)
#pragma unroll
      for (int j = 0; j < 4; ++j) {
        const int tok = (int)arow0 + wr * 64 + m * 16 + lhi * 4 + j;
#pragma unroll
        for (int n = 0; n < 4; ++n) {
          const int gcol = (int)brow0 + wc * 64 + n * 16 + llo;
          out[(size_t)tok * 768 + gcol] = acc[m][n][j] + bias[gcol];
        }
      }
  }
}

// ------- fused S = (q*scale) K^T + softmax -> probs f32 + PV -> ao ------
// block = (qt 32 rows, bh). 4 waves; wave w owns S-cols [w*64,w*64+64) per
// 256-col K-chunk. S in regs: acc[4][2][4] f32x4 = 128 VGPR. After softmax,
// per chunk: P (bf16) bounced through padded LDS lp[32][264] (pad -> b128
// reads hit each bank exactly 8x16B = LDS floor), PV accumulated vs global
// vt. Saves the 403 MB probs re-read the separate pv_gemm kernel did.
__global__ __launch_bounds__(256)
void attn_fused(const u16* __restrict__ q, const u16* __restrict__ kin,
                const u16* __restrict__ vt, float* __restrict__ probs,
                u16* __restrict__ ao)
{
  __shared__ u16 lq[32 * 64];
  __shared__ u16 lk[256 * 64];
  __shared__ u16 lp[32 * 264];
  __shared__ float red[4][32];
  const int qt = blockIdx.x, bh = blockIdx.y;
  const int t = threadIdx.x;
  const int w = t >> 6, l = t & 63, lhi = l >> 4, llo = l & 15;

  gload16(q + ((size_t)bh * 1024 + qt * 32) * 64 + t * 8, &lq[t * 8]);
  __syncthreads();

  bf16x8 aq[2][2];
#pragma unroll
  for (int m = 0; m < 2; ++m)
#pragma unroll
    for (int kc = 0; kc < 2; ++kc)
      aq[m][kc] = *(const bf16x8*)&lq[(m * 16 + llo) * 64 + kc * 32 + lhi * 8];

  f32x4 acc[4][2][4];
#pragma unroll
  for (int c = 0; c < 4; ++c)
#pragma unroll
    for (int m = 0; m < 2; ++m)
#pragma unroll
      for (int n = 0; n < 4; ++n) acc[c][m][n] = f32x4{0.f, 0.f, 0.f, 0.f};

#pragma unroll
  for (int c = 0; c < 4; ++c) {
    __syncthreads();  // protect lk reads of previous chunk
#pragma unroll
    for (int r = 0; r < 8; ++r) {
      int idx = r * 256 + t;
      int row = idx >> 3;
      int cb = (idx & 7) * 16;  // byte col in 128B row
      bf16x8 val = *(const bf16x8*)(kin + ((size_t)bh * 1024 + c * 256 + row) * 64 + (idx & 7) * 8);
      *(bf16x8*)((char*)lk + row * 128 + (cb ^ ((row & 7) << 4))) = val;
    }
    __syncthreads();
#pragma unroll
    for (int n = 0; n < 4; ++n) {
      const int row = w * 64 + n * 16 + llo;
      const char* rp = (const char*)lk + row * 128;
      const int sw = (row & 7) << 4;
      bf16x8 b0 = *(const bf16x8*)(rp + ((lhi * 16) ^ sw));
      bf16x8 b1 = *(const bf16x8*)(rp + ((64 + lhi * 16) ^ sw));
#pragma unroll
      for (int m = 0; m < 2; ++m) {
        acc[c][m][n] = __builtin_amdgcn_mfma_f32_16x16x32_bf16(aq[m][0], b0, acc[c][m][n], 0, 0, 0);
        acc[c][m][n] = __builtin_amdgcn_mfma_f32_16x16x32_bf16(aq[m][1], b1, acc[c][m][n], 0, 0, 0);
      }
    }
  }

  // ---- row max: per-lane over its 16 cols, xor-reduce 16 lanes, LDS cross-wave
  float rmx[2][4];
#pragma unroll
  for (int m = 0; m < 2; ++m)
#pragma unroll
    for (int j = 0; j < 4; ++j) {
      float v = -1e30f;
#pragma unroll
      for (int c = 0; c < 4; ++c)
#pragma unroll
        for (int n = 0; n < 4; ++n) v = fmaxf(v, acc[c][m][n][j]);
      rmx[m][j] = v;
    }
#pragma unroll
  for (int msk = 1; msk < 16; msk <<= 1)
#pragma unroll
    for (int m = 0; m < 2; ++m)
#pragma unroll
      for (int j = 0; j < 4; ++j)
        rmx[m][j] = fmaxf(rmx[m][j], __shfl_xor(rmx[m][j], msk));
  if (llo == 0) {
#pragma unroll
    for (int m = 0; m < 2; ++m)
#pragma unroll
      for (int j = 0; j < 4; ++j) red[w][m * 16 + lhi * 4 + j] = rmx[m][j];
  }
  __syncthreads();
  float fmx[2][4];
#pragma unroll
  for (int m = 0; m < 2; ++m)
#pragma unroll
    for (int j = 0; j < 4; ++j) {
      int r = m * 16 + lhi * 4 + j;
      fmx[m][j] = fmaxf(fmaxf(red[0][r], red[1][r]), fmaxf(red[2][r], red[3][r]));
    }
  __syncthreads();  // before reusing red for sums

  // ---- exp + row sum
  float rsm[2][4];
#pragma unroll
  for (int m = 0; m < 2; ++m)
#pragma unroll
    for (int j = 0; j < 4; ++j) rsm[m][j] = 0.f;
#pragma unroll
  for (int c = 0; c < 4; ++c)
#pragma unroll
    for (int n = 0; n < 4; ++n)
#pragma unroll
      for (int m = 0; m < 2; ++m)
#pragma unroll
        for (int j = 0; j < 4; ++j) {
          float e = __expf(acc[c][m][n][j] - fmx[m][j]);
          acc[c][m][n][j] = e;
          rsm[m][j] += e;
        }
#pragma unroll
  for (int msk = 1; msk < 16; msk <<= 1)
#pragma unroll
    for (int m = 0; m < 2; ++m)
#pragma unroll
      for (int j = 0; j < 4; ++j) rsm[m][j] += __shfl_xor(rsm[m][j], msk);
  if (llo == 0) {
#pragma unroll
    for (int m = 0; m < 2; ++m)
#pragma unroll
      for (int j = 0; j < 4; ++j) red[w][m * 16 + lhi * 4 + j] = rsm[m][j];
  }
  __syncthreads();
  float inv[2][4];
#pragma unroll
  for (int m = 0; m < 2; ++m)
#pragma unroll
    for (int j = 0; j < 4; ++j) {
      int r = m * 16 + lhi * 4 + j;
      inv[m][j] = 1.0f / (red[0][r] + red[1][r] + red[2][r] + red[3][r]);
    }

  // ---- per chunk: write probs (f32, mandatory output) + P->LDS bf16 -> PV
  const int b = bh / 12, h = bh % 12;
  const u16* vb = vt + (size_t)bh * 65536;
  float* pb = probs + ((size_t)bh * 1024 + qt * 32) * 1024;
  f32x4 acco[2];
  acco[0] = f32x4{0.f, 0.f, 0.f, 0.f};
  acco[1] = f32x4{0.f, 0.f, 0.f, 0.f};

#pragma unroll
  for (int c = 0; c < 4; ++c) {
    __syncthreads();  // previous chunk's lp reads complete
#pragma unroll
    for (int n = 0; n < 4; ++n) {
      const int kloc = w * 64 + n * 16 + llo;
#pragma unroll
      for (int m = 0; m < 2; ++m)
#pragma unroll
        for (int j = 0; j < 4; ++j) {
          const int r = m * 16 + lhi * 4 + j;
          const float p = acc[c][m][n][j] * inv[m][j];
          pb[(size_t)r * 1024 + c * 256 + kloc] = p;
          lp[r * 264 + kloc] = f2bf(p);
        }
    }
    __syncthreads();  // publish lp
#pragma unroll
    for (int ks = 0; ks < 8; ++ks) {
      bf16x8 a0 = *(const bf16x8*)&lp[llo * 264 + ks * 32 + lhi * 8];
      bf16x8 a1 = *(const bf16x8*)&lp[(16 + llo) * 264 + ks * 32 + lhi * 8];
      bf16x8 v = *(const bf16x8*)(vb + (size_t)(w * 16 + llo) * 1024 + c * 256 + ks * 32 + lhi * 8);
      acco[0] = __builtin_amdgcn_mfma_f32_16x16x32_bf16(a0, v, acco[0], 0, 0, 0);
      acco[1] = __builtin_amdgcn_mfma_f32_16x16x32_bf16(a1, v, acco[1], 0, 0, 0);
    }
  }

  // ---- write ao (bf16, layout [b, n, h*64+d] for the proj GEMM)
#pragma unroll
  for (int m = 0; m < 2; ++m)
#pragma unroll
    for (int j = 0; j < 4; ++j) {
      const int ntok = qt * 32 + m * 16 + lhi * 4 + j;
      const int d = w * 16 + llo;
      ao[((size_t)(b * 1024 + ntok)) * 768 + h * 64 + d] = f2bf(acco[m][j]);
    }
}

// ------------------------------- launch --------------------------------
extern "C" void kernel_launch(void* const* d_in, const int* in_sizes, int n_in,
                              void* d_out, int out_size, void* d_ws, size_t ws_size,
                              hipStream_t stream) {
  const float* x     = (const float*)d_in[0];
  const float* se    = (const float*)d_in[1];
  const float* wqkv  = (const float*)d_in[2];
  const float* wproj = (const float*)d_in[3];
  const float* bproj = (const float*)d_in[4];
  float* out = (float*)d_out;
  float* probs = out + 6291456;

  if (ws_size < 67633152) return;  // need ~64.5 MB scratch
  char* ws = (char*)d_ws;
  u16* xb     = (u16*)(ws);
  u16* wqkvb  = (u16*)(ws + 12582912);
  u16* wprojb = (u16*)(ws + 16121856);
  u16* qb     = (u16*)(ws + 17301504);
  u16* kb     = (u16*)(ws + 29884416);
  u16* vtb    = (u16*)(ws + 42467328);
  u16* aob    = (u16*)(ws + 55050240);

  cvt_f32_bf16<<<6144, 256, 0, stream>>>(x, xb, 1572864);
  cvt_f32_bf16<<<1728, 256, 0, stream>>>(wqkv, wqkvb, 442368);
  cvt_f32_bf16<<<576, 256, 0, stream>>>(wproj, wprojb, 147456);
  gemm128<0><<<dim3(64, 18), 256, 0, stream>>>(xb, wqkvb, 768, se, qb, kb, vtb, nullptr, nullptr);
  attn_fused<<<dim3(32, 96), 256, 0, stream>>>(qb, kb, vtb, probs, aob);
  gemm128<1><<<dim3(64, 6), 256, 0, stream>>>(aob, wprojb, 768, nullptr, nullptr, nullptr, nullptr, bproj, out);
}